// Round 3
// baseline (5335.773 us; speedup 1.0000x reference)
//
#include <hip/hip_runtime.h>

typedef unsigned short u16;
typedef __attribute__((ext_vector_type(8))) short short8;
typedef __attribute__((ext_vector_type(4))) short short4v;
typedef __attribute__((ext_vector_type(4))) float f32x4;

// ---------- sizes ----------
#define BB 64
#define SS 256
#define HH 1024
#define NG 3072                 // 3H
#define KK 1024
#define NOUT ((size_t)BB * SS * HH)

// ws layout (bytes)
#define OFF_GSUM 0ull
#define OFF_HB0 100663296ull
#define OFF_HB1 100794368ull
#define OFF_BAR 100925440ull
#define OFF_FLAG 100925504ull
#define WS_NEED 100925568ull

__device__ __forceinline__ float bf2f(u16 x) {
  unsigned u = ((unsigned)x) << 16;
  float f;
  __builtin_memcpy(&f, &u, 4);
  return f;
}
__device__ __forceinline__ u16 f2bf(float f) {
  unsigned u;
  __builtin_memcpy(&u, &f, 4);
  u = (u + 0x7fffu + ((u >> 16) & 1u)) >> 16;
  return (u16)u;
}
template <int F32>
__device__ __forceinline__ float ldval(const void* p, size_t i) {
  return F32 ? ((const float*)p)[i] : bf2f(((const u16*)p)[i]);
}
__device__ __forceinline__ float sigmoidf_(float x) {
  return __builtin_amdgcn_rcpf(1.f + __expf(-x));
}
__device__ __forceinline__ float tanhf_(float x) {
  return 2.f * __builtin_amdgcn_rcpf(1.f + __expf(-2.f * x)) - 1.f;
}

typedef const __attribute__((address_space(1))) void* gcptr;
typedef __attribute__((address_space(3))) void* lptr;

// ================= dtype detector =================
// weight_ih ~ U(-1/32,1/32). bf16 buffer: every u16 word has exp field < 128.
// f32 buffer: even words are mantissa low-halves -> ~50% have exp field >= 128.
__global__ void detect_kernel(const u16* __restrict__ w, unsigned* __restrict__ flag) {
  if (threadIdx.x == 0 && blockIdx.x == 0) {
    int hi = 0;
    for (int i = 0; i < 256; ++i) hi += (((w[i] >> 7) & 0xFF) >= 128) ? 1 : 0;
    *flag = (hi > 16) ? 1u : 0u;   // 1 = float32 buffers
  }
}

// ================= GEMM: gsum = X@Wih^T + b_ih (+F0@Wf0^T + F1@Wf1^T + b_f0 + b_f1 on cols<2048)
template <int F32>
__global__ __launch_bounds__(256) void gemm_fused(
    const void* __restrict__ Xv, const void* __restrict__ F0v, const void* __restrict__ F1v,
    const void* __restrict__ Wihv, const void* __restrict__ Wf0v, const void* __restrict__ Wf1v,
    const void* __restrict__ bihv, const void* __restrict__ bf0v, const void* __restrict__ bf1v,
    u16* __restrict__ C, const unsigned* __restrict__ flag) {
  if ((*flag != 0u) != (F32 != 0)) return;   // uniform self-gate on detected dtype
  __shared__ __align__(16) u16 ldsA[128 * 32];
  __shared__ __align__(16) u16 ldsB[128 * 32];
  const int t = threadIdx.x;
  const int nwg = gridDim.x;                  // 3072 (divisible by 8)
  const int cpx = nwg >> 3;
  const int wg = (blockIdx.x & 7) * cpx + (blockIdx.x >> 3);   // XCD-contiguous chunks
  const int ntn = NG / 128;                   // 24
  const int m0 = (wg / ntn) * 128;
  const int n0 = (wg % ntn) * 128;
  const int lane = t & 63, wv = t >> 6;
  const int wm = wv >> 1, wn = wv & 1;

  f32x4 acc[4][4] = {};

  const int fi0 = t, fi1 = t + 256;
  const int r0 = fi0 >> 2, c0 = (fi0 & 3) * 8;
  const int r1 = fi1 >> 2, c1 = (fi1 & 3) * 8;

  const int nsrc = (n0 < 2048) ? 3 : 1;
  for (int src = 0; src < nsrc; ++src) {
    const void* Ap = (src == 0) ? Xv : ((src == 1) ? F0v : F1v);
    const void* Wp = (src == 0) ? Wihv : ((src == 1) ? Wf0v : Wf1v);
    for (int k0 = 0; k0 < KK; k0 += 32) {
      if (F32) {
        // reg-staged: load f32, convert, ds_write. 128 rows x 8 quads = 1024 slots.
        const float* Af = (const float*)Ap + (size_t)m0 * KK;
        const float* Wf = (const float*)Wp + (size_t)n0 * KK;
#pragma unroll
        for (int it = 0; it < 4; ++it) {
          int idx = t + it * 256;
          int r = idx >> 3, q = idx & 7;
          f32x4 va = *(const f32x4*)(Af + (size_t)r * KK + k0 + q * 4);
          f32x4 vb = *(const f32x4*)(Wf + (size_t)r * KK + k0 + q * 4);
          short4v sa, sb;
#pragma unroll
          for (int j = 0; j < 4; ++j) { sa[j] = (short)f2bf(va[j]); sb[j] = (short)f2bf(vb[j]); }
          *(short4v*)&ldsA[r * 32 + q * 4] = sa;
          *(short4v*)&ldsB[r * 32 + q * 4] = sb;
        }
      } else {
        const u16* Ab = (const u16*)Ap + (size_t)m0 * KK;
        const u16* Wb = (const u16*)Wp + (size_t)n0 * KK;
        __builtin_amdgcn_global_load_lds((gcptr)(Ab + (size_t)r0 * KK + k0 + c0), (lptr)(&ldsA[fi0 * 8]), 16, 0, 0);
        __builtin_amdgcn_global_load_lds((gcptr)(Ab + (size_t)r1 * KK + k0 + c1), (lptr)(&ldsA[fi1 * 8]), 16, 0, 0);
        __builtin_amdgcn_global_load_lds((gcptr)(Wb + (size_t)r0 * KK + k0 + c0), (lptr)(&ldsB[fi0 * 8]), 16, 0, 0);
        __builtin_amdgcn_global_load_lds((gcptr)(Wb + (size_t)r1 * KK + k0 + c1), (lptr)(&ldsB[fi1 * 8]), 16, 0, 0);
      }
      __syncthreads();
      short8 af[4], bw[4];
#pragma unroll
      for (int i = 0; i < 4; ++i) {
        af[i] = *(const short8*)&ldsA[(wm * 64 + i * 16 + (lane & 15)) * 32 + (lane >> 4) * 8];
        bw[i] = *(const short8*)&ldsB[(wn * 64 + i * 16 + (lane & 15)) * 32 + (lane >> 4) * 8];
      }
#pragma unroll
      for (int i = 0; i < 4; ++i)
#pragma unroll
        for (int j = 0; j < 4; ++j)
          acc[i][j] = __builtin_amdgcn_mfma_f32_16x16x32_bf16(af[i], bw[j], acc[i][j], 0, 0, 0);
      __syncthreads();
    }
  }
#pragma unroll
  for (int j = 0; j < 4; ++j) {
    const int col = n0 + wn * 64 + j * 16 + (lane & 15);
    float bias = ldval<F32>(bihv, (size_t)col);
    if (col < 2048) bias += ldval<F32>(bf0v, (size_t)col) + ldval<F32>(bf1v, (size_t)col);
#pragma unroll
    for (int i = 0; i < 4; ++i) {
      const int row = m0 + wm * 64 + i * 16 + (lane >> 4) * 4;
#pragma unroll
      for (int r = 0; r < 4; ++r)
        C[(size_t)(row + r) * NG + col] = f2bf(acc[i][j][r] + bias);
    }
  }
}

// ================= barrier =================
__device__ __forceinline__ void grid_sync(unsigned* bar, unsigned target) {
  __syncthreads();          // all waves' stores drained (vmcnt(0) before s_barrier)
  __threadfence();          // release: write back dirty L2 to coherence point
  if (threadIdx.x == 0) {
    __hip_atomic_fetch_add(bar, 1u, __ATOMIC_RELEASE, __HIP_MEMORY_SCOPE_AGENT);
    while (__hip_atomic_load(bar, __ATOMIC_RELAXED, __HIP_MEMORY_SCOPE_AGENT) < target) {
      __builtin_amdgcn_s_sleep(1);
    }
  }
  __syncthreads();
  __threadfence();          // acquire: invalidate stale L1/L2 lines before reading h
}

// ================= scan: weight-stationary persistent GRU recurrence =================
template <int F32>
__global__ __launch_bounds__(256, 1) void scan_kernel(
    const u16* __restrict__ gsum, const void* __restrict__ Whhv, const void* __restrict__ bhhv,
    u16* __restrict__ h0buf, u16* __restrict__ h1buf,
    void* __restrict__ outv, unsigned* __restrict__ bar, const unsigned* __restrict__ flag) {
  if ((*flag != 0u) != (F32 != 0)) return;   // uniform self-gate
  extern __shared__ u16 wlds[];  // 48*1024 bf16 = 96KB
  const int t = threadIdx.x, w = blockIdx.x;
  const int j0 = w * 16;
  // stage weights (once): row q = g*16+i  <- Whh[g*1024 + j0 + i][:], XOR-swizzled
  for (int c = t; c < 48 * 128; c += 256) {
    int q = c >> 7, chunk = c & 127;
    int g = q >> 4, i = q & 15;
    short8 v;
    if (F32) {
      const float* wf = (const float*)Whhv + ((size_t)(g * 1024 + j0 + i)) * 1024 + chunk * 8;
      f32x4 a = *(const f32x4*)wf, b = *(const f32x4*)(wf + 4);
#pragma unroll
      for (int j = 0; j < 4; ++j) { v[j] = (short)f2bf(a[j]); v[4 + j] = (short)f2bf(b[j]); }
    } else {
      v = *(const short8*)((const u16*)Whhv + ((size_t)(g * 1024 + j0 + i)) * 1024 + chunk * 8);
    }
    *(short8*)((char*)wlds + q * 2048 + ((chunk * 16) ^ ((i & 7) << 4))) = v;
  }
  const int lane = t & 63, wv = t >> 6;
  const int jl = j0 + (lane & 15);
  const int mb = wv * 16;
  const float bhr = ldval<F32>(bhhv, (size_t)jl);
  const float bhi = ldval<F32>(bhhv, (size_t)(1024 + jl));
  const float bhn = ldval<F32>(bhhv, (size_t)(2048 + jl));
  __syncthreads();

  float hreg[4] = {0.f, 0.f, 0.f, 0.f};
  const u16* hb[2] = {h0buf, h1buf};
  u16* hbw[2] = {h0buf, h1buf};
  int cur = 0;

  const int bi = lane & 15;
  const int kb = (lane >> 4) * 16;          // byte offset of lane's 16B k-chunk
  const int sw = (bi & 7) << 4;             // XOR swizzle mask
  const char* wbytes = (const char*)wlds;
  const char* s0 = wbytes + (size_t)(0 + bi) * 2048;
  const char* s1 = wbytes + (size_t)(16 + bi) * 2048;
  const char* s2 = wbytes + (size_t)(32 + bi) * 2048;

  // prefetch gsum for step 0
  float pg[4][3];
#pragma unroll
  for (int r = 0; r < 4; ++r) {
    size_t m = (size_t)(mb + (lane >> 4) * 4 + r) * 256 + 0;
    pg[r][0] = bf2f(gsum[m * 3072 + jl]);
    pg[r][1] = bf2f(gsum[m * 3072 + 1024 + jl]);
    pg[r][2] = bf2f(gsum[m * 3072 + 2048 + jl]);
  }

  for (int s = 0; s < 256; ++s) {
    f32x4 ar = {0.f, 0.f, 0.f, 0.f};
    f32x4 ai = {0.f, 0.f, 0.f, 0.f};
    f32x4 an = {0.f, 0.f, 0.f, 0.f};
    if (s > 0) {
      const u16* h = hb[cur];
      const u16* ap = h + (size_t)(mb + (lane & 15)) * 1024 + (lane >> 4) * 8;
#pragma unroll
      for (int kk = 0; kk < 32; ++kk) {
        short8 a = *(const short8*)(ap + kk * 32);
        int ko = kk * 64 + kb;
        short8 br = *(const short8*)(s0 + (ko ^ sw));
        short8 bib = *(const short8*)(s1 + (ko ^ sw));
        short8 bn = *(const short8*)(s2 + (ko ^ sw));
        ar = __builtin_amdgcn_mfma_f32_16x16x32_bf16(a, br, ar, 0, 0, 0);
        ai = __builtin_amdgcn_mfma_f32_16x16x32_bf16(a, bib, ai, 0, 0, 0);
        an = __builtin_amdgcn_mfma_f32_16x16x32_bf16(a, bn, an, 0, 0, 0);
      }
    }
    u16* hw = hbw[cur ^ 1];
#pragma unroll
    for (int r = 0; r < 4; ++r) {
      int b = mb + (lane >> 4) * 4 + r;
      size_t m = (size_t)b * 256 + s;
      float rg = sigmoidf_(pg[r][0] + ar[r] + bhr);
      float ig = sigmoidf_(pg[r][1] + ai[r] + bhi);
      float ng = tanhf_(pg[r][2] + rg * (an[r] + bhn));
      float hy = ng + ig * (hreg[r] - ng);
      hreg[r] = hy;
      hw[(size_t)b * 1024 + jl] = f2bf(hy);
      if (F32) ((float*)outv)[m * 1024 + jl] = hy;
      else     ((u16*)outv)[m * 1024 + jl] = f2bf(hy);
    }
    // prefetch gsum for s+1 before the barrier (hidden under spin)
    if (s < 255) {
#pragma unroll
      for (int r = 0; r < 4; ++r) {
        size_t m = (size_t)(mb + (lane >> 4) * 4 + r) * 256 + (s + 1);
        pg[r][0] = bf2f(gsum[m * 3072 + jl]);
        pg[r][1] = bf2f(gsum[m * 3072 + 1024 + jl]);
        pg[r][2] = bf2f(gsum[m * 3072 + 2048 + jl]);
      }
    }
    grid_sync(bar, (unsigned)(64 * (s + 1)));
    cur ^= 1;
  }
#pragma unroll
  for (int r = 0; r < 4; ++r) {
    int b = mb + (lane >> 4) * 4 + r;
    if (F32) ((float*)outv)[NOUT + (size_t)b * 1024 + jl] = hreg[r];
    else     ((u16*)outv)[NOUT + (size_t)b * 1024 + jl] = f2bf(hreg[r]);
  }
}

extern "C" void kernel_launch(void* const* d_in, const int* in_sizes, int n_in,
                              void* d_out, int out_size, void* d_ws, size_t ws_size,
                              hipStream_t stream) {
  if (ws_size < WS_NEED) return;
  const void* x   = d_in[0];
  const void* f0  = d_in[1];
  const void* f1  = d_in[2];
  const void* wih = d_in[3];
  const void* whh = d_in[4];
  const void* wf0 = d_in[5];
  const void* wf1 = d_in[6];
  const void* bih = d_in[7];
  const void* bhh = d_in[8];
  const void* bf0 = d_in[9];
  const void* bf1 = d_in[10];

  char* ws = (char*)d_ws;
  u16* gsum = (u16*)(ws + OFF_GSUM);
  u16* hb0 = (u16*)(ws + OFF_HB0);
  u16* hb1 = (u16*)(ws + OFF_HB1);
  unsigned* bar = (unsigned*)(ws + OFF_BAR);
  unsigned* flag = (unsigned*)(ws + OFF_FLAG);

  hipMemsetAsync(bar, 0, 128, stream);      // bar + flag region
  hipMemsetAsync(hb0, 0, 131072, stream);   // deterministic h buffers each launch
  hipMemsetAsync(hb1, 0, 131072, stream);

  detect_kernel<<<dim3(1), dim3(64), 0, stream>>>((const u16*)wih, flag);

  gemm_fused<0><<<dim3(3072), dim3(256), 0, stream>>>(x, f0, f1, wih, wf0, wf1, bih, bf0, bf1, gsum, flag);
  gemm_fused<1><<<dim3(3072), dim3(256), 0, stream>>>(x, f0, f1, wih, wf0, wf1, bih, bf0, bf1, gsum, flag);

  hipFuncSetAttribute(reinterpret_cast<const void*>(&scan_kernel<0>),
                      hipFuncAttributeMaxDynamicSharedMemorySize, 98304);
  hipFuncSetAttribute(reinterpret_cast<const void*>(&scan_kernel<1>),
                      hipFuncAttributeMaxDynamicSharedMemorySize, 98304);
  scan_kernel<0><<<dim3(64), dim3(256), 98304, stream>>>(gsum, whh, bhh, hb0, hb1, d_out, bar, flag);
  scan_kernel<1><<<dim3(64), dim3(256), 98304, stream>>>(gsum, whh, bhh, hb0, hb1, d_out, bar, flag);
}

// Round 4
// 2843.298 us; speedup vs baseline: 1.8766x; 1.8766x over previous
//
#include <hip/hip_runtime.h>

typedef unsigned short u16;
typedef __attribute__((ext_vector_type(8))) short short8;
typedef __attribute__((ext_vector_type(4))) short short4v;
typedef __attribute__((ext_vector_type(4))) float f32x4;

// ---------- sizes ----------
#define BB 64
#define SS 256
#define HH 1024
#define NG 3072                 // 3H
#define KK 1024
#define NOUT ((size_t)BB * SS * HH)

// ws layout (bytes)
#define OFF_GSUM 0ull
#define OFF_HB0 100663296ull
#define OFF_HB1 100794368ull
#define OFF_BAR 100925440ull
#define OFF_FLAG 100925504ull
#define WS_NEED 100925568ull

__device__ __forceinline__ float bf2f(u16 x) {
  unsigned u = ((unsigned)x) << 16;
  float f;
  __builtin_memcpy(&f, &u, 4);
  return f;
}
__device__ __forceinline__ u16 f2bf(float f) {
  unsigned u;
  __builtin_memcpy(&u, &f, 4);
  u = (u + 0x7fffu + ((u >> 16) & 1u)) >> 16;
  return (u16)u;
}
template <int F32>
__device__ __forceinline__ float ldval(const void* p, size_t i) {
  return F32 ? ((const float*)p)[i] : bf2f(((const u16*)p)[i]);
}
__device__ __forceinline__ float sigmoidf_(float x) {
  return __builtin_amdgcn_rcpf(1.f + __expf(-x));
}
__device__ __forceinline__ float tanhf_(float x) {
  return 2.f * __builtin_amdgcn_rcpf(1.f + __expf(-2.f * x)) - 1.f;
}

typedef const __attribute__((address_space(1))) void* gcptr;
typedef __attribute__((address_space(3))) void* lptr;

// ================= dtype detector =================
__global__ void detect_kernel(const u16* __restrict__ w, unsigned* __restrict__ flag) {
  if (threadIdx.x == 0 && blockIdx.x == 0) {
    int hi = 0;
    for (int i = 0; i < 256; ++i) hi += (((w[i] >> 7) & 0xFF) >= 128) ? 1 : 0;
    *flag = (hi > 16) ? 1u : 0u;   // 1 = float32 buffers
  }
}

// ================= GEMM: gsum = X@Wih^T + b_ih (+F0@Wf0^T + F1@Wf1^T + biases on cols<2048)
template <int F32>
__global__ __launch_bounds__(256) void gemm_fused(
    const void* __restrict__ Xv, const void* __restrict__ F0v, const void* __restrict__ F1v,
    const void* __restrict__ Wihv, const void* __restrict__ Wf0v, const void* __restrict__ Wf1v,
    const void* __restrict__ bihv, const void* __restrict__ bf0v, const void* __restrict__ bf1v,
    u16* __restrict__ C, const unsigned* __restrict__ flag) {
  if ((*flag != 0u) != (F32 != 0)) return;   // uniform self-gate on detected dtype
  __shared__ __align__(16) u16 ldsA[128 * 32];
  __shared__ __align__(16) u16 ldsB[128 * 32];
  const int t = threadIdx.x;
  const int nwg = gridDim.x;                  // 3072 (divisible by 8)
  const int cpx = nwg >> 3;
  const int wg = (blockIdx.x & 7) * cpx + (blockIdx.x >> 3);   // XCD-contiguous chunks
  const int ntn = NG / 128;                   // 24
  const int m0 = (wg / ntn) * 128;
  const int n0 = (wg % ntn) * 128;
  const int lane = t & 63, wv = t >> 6;
  const int wm = wv >> 1, wn = wv & 1;

  f32x4 acc[4][4] = {};

  const int fi0 = t, fi1 = t + 256;
  const int r0 = fi0 >> 2, c0 = (fi0 & 3) * 8;
  const int r1 = fi1 >> 2, c1 = (fi1 & 3) * 8;

  const int nsrc = (n0 < 2048) ? 3 : 1;
  for (int src = 0; src < nsrc; ++src) {
    const void* Ap = (src == 0) ? Xv : ((src == 1) ? F0v : F1v);
    const void* Wp = (src == 0) ? Wihv : ((src == 1) ? Wf0v : Wf1v);
    for (int k0 = 0; k0 < KK; k0 += 32) {
      if (F32) {
        const float* Af = (const float*)Ap + (size_t)m0 * KK;
        const float* Wf = (const float*)Wp + (size_t)n0 * KK;
#pragma unroll
        for (int it = 0; it < 4; ++it) {
          int idx = t + it * 256;
          int r = idx >> 3, q = idx & 7;
          f32x4 va = *(const f32x4*)(Af + (size_t)r * KK + k0 + q * 4);
          f32x4 vb = *(const f32x4*)(Wf + (size_t)r * KK + k0 + q * 4);
          short4v sa, sb;
#pragma unroll
          for (int j = 0; j < 4; ++j) { sa[j] = (short)f2bf(va[j]); sb[j] = (short)f2bf(vb[j]); }
          *(short4v*)&ldsA[r * 32 + q * 4] = sa;
          *(short4v*)&ldsB[r * 32 + q * 4] = sb;
        }
      } else {
        const u16* Ab = (const u16*)Ap + (size_t)m0 * KK;
        const u16* Wb = (const u16*)Wp + (size_t)n0 * KK;
        __builtin_amdgcn_global_load_lds((gcptr)(Ab + (size_t)r0 * KK + k0 + c0), (lptr)(&ldsA[fi0 * 8]), 16, 0, 0);
        __builtin_amdgcn_global_load_lds((gcptr)(Ab + (size_t)r1 * KK + k0 + c1), (lptr)(&ldsA[fi1 * 8]), 16, 0, 0);
        __builtin_amdgcn_global_load_lds((gcptr)(Wb + (size_t)r0 * KK + k0 + c0), (lptr)(&ldsB[fi0 * 8]), 16, 0, 0);
        __builtin_amdgcn_global_load_lds((gcptr)(Wb + (size_t)r1 * KK + k0 + c1), (lptr)(&ldsB[fi1 * 8]), 16, 0, 0);
      }
      __syncthreads();
      short8 af[4], bw[4];
#pragma unroll
      for (int i = 0; i < 4; ++i) {
        af[i] = *(const short8*)&ldsA[(wm * 64 + i * 16 + (lane & 15)) * 32 + (lane >> 4) * 8];
        bw[i] = *(const short8*)&ldsB[(wn * 64 + i * 16 + (lane & 15)) * 32 + (lane >> 4) * 8];
      }
#pragma unroll
      for (int i = 0; i < 4; ++i)
#pragma unroll
        for (int j = 0; j < 4; ++j)
          acc[i][j] = __builtin_amdgcn_mfma_f32_16x16x32_bf16(af[i], bw[j], acc[i][j], 0, 0, 0);
      __syncthreads();
    }
  }
#pragma unroll
  for (int j = 0; j < 4; ++j) {
    const int col = n0 + wn * 64 + j * 16 + (lane & 15);
    float bias = ldval<F32>(bihv, (size_t)col);
    if (col < 2048) bias += ldval<F32>(bf0v, (size_t)col) + ldval<F32>(bf1v, (size_t)col);
#pragma unroll
    for (int i = 0; i < 4; ++i) {
      const int row = m0 + wm * 64 + i * 16 + (lane >> 4) * 4;
#pragma unroll
      for (int r = 0; r < 4; ++r)
        C[(size_t)(row + r) * NG + col] = f2bf(acc[i][j][r] + bias);
    }
  }
}

// ================= barrier (fence-free) =================
// Cross-WG data (h) moves via sc0/sc1 write-through stores & bypass loads, so
// NO cache fence (wbl2/inv) is needed here. vmcnt(0) before s_barrier (explicit
// + compiler's) guarantees write-through stores have reached the coherence
// point before thread0's arrive-add.
__device__ __forceinline__ void grid_sync(unsigned* bar, unsigned target) {
  asm volatile("s_waitcnt vmcnt(0)" ::: "memory");
  __syncthreads();
  if (threadIdx.x == 0) {
    __hip_atomic_fetch_add(bar, 1u, __ATOMIC_RELAXED, __HIP_MEMORY_SCOPE_AGENT);
    unsigned v;
    do {
      __builtin_amdgcn_s_sleep(2);
      asm volatile("global_load_dword %0, %1, off sc0 sc1\n\ts_waitcnt vmcnt(0)"
                   : "=v"(v) : "v"(bar));
    } while (v < target);
  }
  __syncthreads();
}

// ================= scan: weight-stationary persistent GRU recurrence =================
// 64 WGs x 256 thr. WG w owns hidden cols [w*16, w*16+16). Whh strips r,i,n in LDS
// as [48 rows][2048B], full-rank XOR swizzle (byte ^= row<<4): per 16-lane phase
// group slots are distinct mod 16 -> 2-way (free) bank access.
#define ISSUE8(buf, bkk)                                                        \
  _Pragma("unroll")                                                             \
  for (int i_ = 0; i_ < 8; ++i_)                                                \
    asm volatile("global_load_dwordx4 %0, %1, off sc0 sc1"                      \
                 : "=v"(buf[i_]) : "v"(ap + ((bkk) + i_) * 32));

#define CONSUME8(buf, bkk)                                                      \
  _Pragma("unroll")                                                             \
  for (int i_ = 0; i_ < 8; ++i_) {                                              \
    const int ko_ = ((bkk) + i_) * 64 + kb;                                     \
    short8 br_ = *(const short8*)(s0 + (ko_ ^ sw));                             \
    short8 bj_ = *(const short8*)(s1 + (ko_ ^ sw));                             \
    short8 bn_ = *(const short8*)(s2 + (ko_ ^ sw));                             \
    ar = __builtin_amdgcn_mfma_f32_16x16x32_bf16(buf[i_], br_, ar, 0, 0, 0);    \
    ai = __builtin_amdgcn_mfma_f32_16x16x32_bf16(buf[i_], bj_, ai, 0, 0, 0);    \
    an = __builtin_amdgcn_mfma_f32_16x16x32_bf16(buf[i_], bn_, an, 0, 0, 0);    \
  }

template <int F32>
__global__ __launch_bounds__(256, 1) void scan_kernel(
    const u16* __restrict__ gsum, const void* __restrict__ Whhv, const void* __restrict__ bhhv,
    u16* __restrict__ h0buf, u16* __restrict__ h1buf,
    void* __restrict__ outv, unsigned* __restrict__ bar, const unsigned* __restrict__ flag) {
  if ((*flag != 0u) != (F32 != 0)) return;   // uniform self-gate
  extern __shared__ u16 wlds[];  // 48*1024 bf16 = 96KB
  const int t = threadIdx.x, w = blockIdx.x;
  const int j0 = w * 16;
  // stage weights (once): row q = g*16+i  <- Whh[g*1024 + j0 + i][:], byte ^= (i<<4)
  for (int c = t; c < 48 * 128; c += 256) {
    int q = c >> 7, chunk = c & 127;
    int g = q >> 4, i = q & 15;
    short8 v;
    if (F32) {
      const float* wf = (const float*)Whhv + ((size_t)(g * 1024 + j0 + i)) * 1024 + chunk * 8;
      f32x4 a = *(const f32x4*)wf, b = *(const f32x4*)(wf + 4);
#pragma unroll
      for (int j = 0; j < 4; ++j) { v[j] = (short)f2bf(a[j]); v[4 + j] = (short)f2bf(b[j]); }
    } else {
      v = *(const short8*)((const u16*)Whhv + ((size_t)(g * 1024 + j0 + i)) * 1024 + chunk * 8);
    }
    *(short8*)((char*)wlds + q * 2048 + ((chunk * 16) ^ (i << 4))) = v;
  }
  const int lane = t & 63;
  const int bi = lane & 15;
  const int quad = lane >> 4;
  const int jl = j0 + bi;
  const int mb = (t >> 6) * 16;
  const float bhr = ldval<F32>(bhhv, (size_t)jl);
  const float bhi = ldval<F32>(bhhv, (size_t)(1024 + jl));
  const float bhn = ldval<F32>(bhhv, (size_t)(2048 + jl));
  __syncthreads();

  float hreg[4] = {0.f, 0.f, 0.f, 0.f};

  const int kb = quad * 16;                 // byte offset of lane's 16B k-chunk
  const int sw = bi << 4;                   // full-rank XOR swizzle
  const char* wbytes = (const char*)wlds;
  const char* s0 = wbytes + (size_t)(0 + bi) * 2048;
  const char* s1 = wbytes + (size_t)(16 + bi) * 2048;
  const char* s2 = wbytes + (size_t)(32 + bi) * 2048;

  // prefetch gsum for step 0 (normal cached loads; gsum is read-once streaming)
  float pg[4][3];
#pragma unroll
  for (int r = 0; r < 4; ++r) {
    size_t m = (size_t)(mb + quad * 4 + r) * 256 + 0;
    pg[r][0] = bf2f(gsum[m * 3072 + jl]);
    pg[r][1] = bf2f(gsum[m * 3072 + 1024 + jl]);
    pg[r][2] = bf2f(gsum[m * 3072 + 2048 + jl]);
  }

  for (int s = 0; s < 256; ++s) {
    f32x4 ar = {0.f, 0.f, 0.f, 0.f};
    f32x4 ai = {0.f, 0.f, 0.f, 0.f};
    f32x4 an = {0.f, 0.f, 0.f, 0.f};
    if (s > 0) {
      const u16* hcur = (s & 1) ? h1buf : h0buf;
      const u16* ap = hcur + (size_t)(mb + bi) * 1024 + quad * 8;
      short8 aA[8], aB[8], aC[8], aD[8];
      __builtin_amdgcn_sched_barrier(0);
      ISSUE8(aA, 0);
      ISSUE8(aB, 8);
      ISSUE8(aC, 16);
      ISSUE8(aD, 24);
      asm volatile("s_waitcnt vmcnt(24)" ::: "memory");
      __builtin_amdgcn_sched_barrier(0);
      CONSUME8(aA, 0);
      asm volatile("s_waitcnt vmcnt(16)" ::: "memory");
      __builtin_amdgcn_sched_barrier(0);
      CONSUME8(aB, 8);
      asm volatile("s_waitcnt vmcnt(8)" ::: "memory");
      __builtin_amdgcn_sched_barrier(0);
      CONSUME8(aC, 16);
      asm volatile("s_waitcnt vmcnt(0)" ::: "memory");
      __builtin_amdgcn_sched_barrier(0);
      CONSUME8(aD, 24);
      __builtin_amdgcn_sched_barrier(0);
    }
    u16* hw = (s & 1) ? h0buf : h1buf;
#pragma unroll
    for (int r = 0; r < 4; ++r) {
      int b = mb + quad * 4 + r;
      size_t m = (size_t)b * 256 + s;
      float rg = sigmoidf_(pg[r][0] + ar[r] + bhr);
      float ig = sigmoidf_(pg[r][1] + ai[r] + bhi);
      float ng = tanhf_(pg[r][2] + rg * (an[r] + bhn));
      float hy = ng + ig * (hreg[r] - ng);
      hreg[r] = hy;
      unsigned hv = (unsigned)f2bf(hy);
      // h: write-through to coherence point (visible to other XCDs' sc1 loads)
      asm volatile("global_store_short %0, %1, off sc0 sc1"
                   :: "v"(hw + (size_t)b * 1024 + jl), "v"(hv) : "memory");
      // out: streaming store, keep L2 clean
      if (F32) __builtin_nontemporal_store(hy, &((float*)outv)[m * 1024 + jl]);
      else     __builtin_nontemporal_store((u16)hv, &((u16*)outv)[m * 1024 + jl]);
    }
    // prefetch gsum for s+1 (before the barrier; hidden under spin)
    if (s < 255) {
#pragma unroll
      for (int r = 0; r < 4; ++r) {
        size_t m = (size_t)(mb + quad * 4 + r) * 256 + (s + 1);
        pg[r][0] = bf2f(gsum[m * 3072 + jl]);
        pg[r][1] = bf2f(gsum[m * 3072 + 1024 + jl]);
        pg[r][2] = bf2f(gsum[m * 3072 + 2048 + jl]);
      }
      grid_sync(bar, (unsigned)(64 * (s + 1)));
    }
  }
#pragma unroll
  for (int r = 0; r < 4; ++r) {
    int b = mb + quad * 4 + r;
    if (F32) __builtin_nontemporal_store(hreg[r], &((float*)outv)[NOUT + (size_t)b * 1024 + jl]);
    else     __builtin_nontemporal_store(f2bf(hreg[r]), &((u16*)outv)[NOUT + (size_t)b * 1024 + jl]);
  }
}

extern "C" void kernel_launch(void* const* d_in, const int* in_sizes, int n_in,
                              void* d_out, int out_size, void* d_ws, size_t ws_size,
                              hipStream_t stream) {
  if (ws_size < WS_NEED) return;
  const void* x   = d_in[0];
  const void* f0  = d_in[1];
  const void* f1  = d_in[2];
  const void* wih = d_in[3];
  const void* whh = d_in[4];
  const void* wf0 = d_in[5];
  const void* wf1 = d_in[6];
  const void* bih = d_in[7];
  const void* bhh = d_in[8];
  const void* bf0 = d_in[9];
  const void* bf1 = d_in[10];

  char* ws = (char*)d_ws;
  u16* gsum = (u16*)(ws + OFF_GSUM);
  u16* hb0 = (u16*)(ws + OFF_HB0);
  u16* hb1 = (u16*)(ws + OFF_HB1);
  unsigned* bar = (unsigned*)(ws + OFF_BAR);
  unsigned* flag = (unsigned*)(ws + OFF_FLAG);

  hipMemsetAsync(bar, 0, 128, stream);      // bar + flag region
  hipMemsetAsync(hb0, 0, 131072, stream);   // deterministic h buffers each launch
  hipMemsetAsync(hb1, 0, 131072, stream);

  detect_kernel<<<dim3(1), dim3(64), 0, stream>>>((const u16*)wih, flag);

  gemm_fused<0><<<dim3(3072), dim3(256), 0, stream>>>(x, f0, f1, wih, wf0, wf1, bih, bf0, bf1, gsum, flag);
  gemm_fused<1><<<dim3(3072), dim3(256), 0, stream>>>(x, f0, f1, wih, wf0, wf1, bih, bf0, bf1, gsum, flag);

  hipFuncSetAttribute(reinterpret_cast<const void*>(&scan_kernel<0>),
                      hipFuncAttributeMaxDynamicSharedMemorySize, 98304);
  hipFuncSetAttribute(reinterpret_cast<const void*>(&scan_kernel<1>),
                      hipFuncAttributeMaxDynamicSharedMemorySize, 98304);
  scan_kernel<0><<<dim3(64), dim3(256), 98304, stream>>>(gsum, whh, bhh, hb0, hb1, d_out, bar, flag);
  scan_kernel<1><<<dim3(64), dim3(256), 98304, stream>>>(gsum, whh, bhh, hb0, hb1, d_out, bar, flag);
}

// Round 5
// 2515.750 us; speedup vs baseline: 2.1209x; 1.1302x over previous
//
#include <hip/hip_runtime.h>

typedef unsigned short u16;
typedef __attribute__((ext_vector_type(8))) short short8;
typedef __attribute__((ext_vector_type(4))) short short4v;
typedef __attribute__((ext_vector_type(4))) float f32x4;

// ---------- sizes ----------
#define BB 64
#define SS 256
#define HH 1024
#define NG 3072                 // 3H
#define KK 1024
#define NOUT ((size_t)BB * SS * HH)

// ws layout (bytes)
#define OFF_GSUM 0ull
#define OFF_HB0 100663296ull
#define OFF_HB1 100794368ull
#define OFF_BAR 100925440ull
#define OFF_FLAG 100925504ull
#define WS_NEED 100925568ull

__device__ __forceinline__ float bf2f(u16 x) {
  unsigned u = ((unsigned)x) << 16;
  float f;
  __builtin_memcpy(&f, &u, 4);
  return f;
}
__device__ __forceinline__ float bf2f_u(unsigned x) {
  unsigned u = x << 16;
  float f;
  __builtin_memcpy(&f, &u, 4);
  return f;
}
__device__ __forceinline__ u16 f2bf(float f) {
  unsigned u;
  __builtin_memcpy(&u, &f, 4);
  u = (u + 0x7fffu + ((u >> 16) & 1u)) >> 16;
  return (u16)u;
}
template <int F32>
__device__ __forceinline__ float ldval(const void* p, size_t i) {
  return F32 ? ((const float*)p)[i] : bf2f(((const u16*)p)[i]);
}
__device__ __forceinline__ float sigmoidf_(float x) {
  return __builtin_amdgcn_rcpf(1.f + __expf(-x));
}
__device__ __forceinline__ float tanhf_(float x) {
  return 2.f * __builtin_amdgcn_rcpf(1.f + __expf(-2.f * x)) - 1.f;
}

typedef const __attribute__((address_space(1))) void* gcptr;
typedef __attribute__((address_space(3))) void* lptr;

// ================= dtype detector =================
__global__ void detect_kernel(const u16* __restrict__ w, unsigned* __restrict__ flag) {
  if (threadIdx.x == 0 && blockIdx.x == 0) {
    int hi = 0;
    for (int i = 0; i < 256; ++i) hi += (((w[i] >> 7) & 0xFF) >= 128) ? 1 : 0;
    *flag = (hi > 16) ? 1u : 0u;   // 1 = float32 buffers
  }
}

// ================= GEMM: gsum = X@Wih^T + b_ih (+F0@Wf0^T + F1@Wf1^T + biases on cols<2048)
template <int F32>
__global__ __launch_bounds__(256) void gemm_fused(
    const void* __restrict__ Xv, const void* __restrict__ F0v, const void* __restrict__ F1v,
    const void* __restrict__ Wihv, const void* __restrict__ Wf0v, const void* __restrict__ Wf1v,
    const void* __restrict__ bihv, const void* __restrict__ bf0v, const void* __restrict__ bf1v,
    u16* __restrict__ C, const unsigned* __restrict__ flag) {
  if ((*flag != 0u) != (F32 != 0)) return;   // uniform self-gate on detected dtype
  __shared__ __align__(16) u16 ldsA[128 * 32];
  __shared__ __align__(16) u16 ldsB[128 * 32];
  const int t = threadIdx.x;
  const int nwg = gridDim.x;                  // 3072 (divisible by 8)
  const int cpx = nwg >> 3;
  const int wg = (blockIdx.x & 7) * cpx + (blockIdx.x >> 3);   // XCD-contiguous chunks
  const int ntn = NG / 128;                   // 24
  const int m0 = (wg / ntn) * 128;
  const int n0 = (wg % ntn) * 128;
  const int lane = t & 63, wv = t >> 6;
  const int wm = wv >> 1, wn = wv & 1;

  f32x4 acc[4][4] = {};

  const int fi0 = t, fi1 = t + 256;
  const int r0 = fi0 >> 2, c0 = (fi0 & 3) * 8;
  const int r1 = fi1 >> 2, c1 = (fi1 & 3) * 8;

  const int nsrc = (n0 < 2048) ? 3 : 1;
  for (int src = 0; src < nsrc; ++src) {
    const void* Ap = (src == 0) ? Xv : ((src == 1) ? F0v : F1v);
    const void* Wp = (src == 0) ? Wihv : ((src == 1) ? Wf0v : Wf1v);
    for (int k0 = 0; k0 < KK; k0 += 32) {
      if (F32) {
        const float* Af = (const float*)Ap + (size_t)m0 * KK;
        const float* Wf = (const float*)Wp + (size_t)n0 * KK;
#pragma unroll
        for (int it = 0; it < 4; ++it) {
          int idx = t + it * 256;
          int r = idx >> 3, q = idx & 7;
          f32x4 va = *(const f32x4*)(Af + (size_t)r * KK + k0 + q * 4);
          f32x4 vb = *(const f32x4*)(Wf + (size_t)r * KK + k0 + q * 4);
          short4v sa, sb;
#pragma unroll
          for (int j = 0; j < 4; ++j) { sa[j] = (short)f2bf(va[j]); sb[j] = (short)f2bf(vb[j]); }
          *(short4v*)&ldsA[r * 32 + q * 4] = sa;
          *(short4v*)&ldsB[r * 32 + q * 4] = sb;
        }
      } else {
        const u16* Ab = (const u16*)Ap + (size_t)m0 * KK;
        const u16* Wb = (const u16*)Wp + (size_t)n0 * KK;
        __builtin_amdgcn_global_load_lds((gcptr)(Ab + (size_t)r0 * KK + k0 + c0), (lptr)(&ldsA[fi0 * 8]), 16, 0, 0);
        __builtin_amdgcn_global_load_lds((gcptr)(Ab + (size_t)r1 * KK + k0 + c1), (lptr)(&ldsA[fi1 * 8]), 16, 0, 0);
        __builtin_amdgcn_global_load_lds((gcptr)(Wb + (size_t)r0 * KK + k0 + c0), (lptr)(&ldsB[fi0 * 8]), 16, 0, 0);
        __builtin_amdgcn_global_load_lds((gcptr)(Wb + (size_t)r1 * KK + k0 + c1), (lptr)(&ldsB[fi1 * 8]), 16, 0, 0);
      }
      __syncthreads();
      short8 af[4], bw[4];
#pragma unroll
      for (int i = 0; i < 4; ++i) {
        af[i] = *(const short8*)&ldsA[(wm * 64 + i * 16 + (lane & 15)) * 32 + (lane >> 4) * 8];
        bw[i] = *(const short8*)&ldsB[(wn * 64 + i * 16 + (lane & 15)) * 32 + (lane >> 4) * 8];
      }
#pragma unroll
      for (int i = 0; i < 4; ++i)
#pragma unroll
        for (int j = 0; j < 4; ++j)
          acc[i][j] = __builtin_amdgcn_mfma_f32_16x16x32_bf16(af[i], bw[j], acc[i][j], 0, 0, 0);
      __syncthreads();
    }
  }
#pragma unroll
  for (int j = 0; j < 4; ++j) {
    const int col = n0 + wn * 64 + j * 16 + (lane & 15);
    float bias = ldval<F32>(bihv, (size_t)col);
    if (col < 2048) bias += ldval<F32>(bf0v, (size_t)col) + ldval<F32>(bf1v, (size_t)col);
#pragma unroll
    for (int i = 0; i < 4; ++i) {
      const int row = m0 + wm * 64 + i * 16 + (lane >> 4) * 4;
#pragma unroll
      for (int r = 0; r < 4; ++r)
        C[(size_t)(row + r) * NG + col] = f2bf(acc[i][j][r] + bias);
    }
  }
}

// ================= scan: weight-stationary persistent GRU, manual vmcnt discipline ===========
// 64 WGs x 256 thr. WG w owns hidden cols [w*16, w*16+16). Whh strips r,i,n in LDS
// as [48 rows][2048B], full-rank XOR swizzle (byte ^= row<<4) -> conflict-free (R4: 0).
// ALL loop vmem is inline asm; counted vmcnt keeps out-stores & gsum loads in flight
// across the raw s_barrier (no compiler vmcnt(0) drain).
#define SB0() __builtin_amdgcn_sched_barrier(0)

#define ISSUE8(buf, bkk)                                                        \
  _Pragma("unroll")                                                             \
  for (int i_ = 0; i_ < 8; ++i_)                                                \
    asm volatile("global_load_dwordx4 %0, %1, off sc0 sc1"                      \
                 : "=v"(buf[i_]) : "v"(ap + ((bkk) + i_) * 32));

#define CONSUME8(buf, bkk)                                                      \
  _Pragma("unroll")                                                             \
  for (int i_ = 0; i_ < 8; ++i_) {                                              \
    const int ko_ = ((bkk) + i_) * 64 + kb;                                     \
    short8 br_ = *(const short8*)(s0 + (ko_ ^ sw));                             \
    short8 bj_ = *(const short8*)(s1 + (ko_ ^ sw));                             \
    short8 bn_ = *(const short8*)(s2 + (ko_ ^ sw));                             \
    ar = __builtin_amdgcn_mfma_f32_16x16x32_bf16(buf[i_], br_, ar, 0, 0, 0);    \
    ai = __builtin_amdgcn_mfma_f32_16x16x32_bf16(buf[i_], bj_, ai, 0, 0, 0);    \
    an = __builtin_amdgcn_mfma_f32_16x16x32_bf16(buf[i_], bn_, an, 0, 0, 0);    \
  }

// 12 gsum loads (bf16 words, zero-extended) for step `snext`
#define ISSUE_GSUM(snext)                                                       \
  _Pragma("unroll")                                                             \
  for (int r_ = 0; r_ < 4; ++r_) {                                              \
    const u16* gp_ = gsum + ((size_t)(mb + quad * 4 + r_) * 256 + (size_t)(snext)) * 3072 + jl; \
    asm volatile("global_load_ushort %0, %1, off" : "=v"(pgu[r_ * 3 + 0]) : "v"(gp_));          \
    asm volatile("global_load_ushort %0, %1, off" : "=v"(pgu[r_ * 3 + 1]) : "v"(gp_ + 1024));   \
    asm volatile("global_load_ushort %0, %1, off" : "=v"(pgu[r_ * 3 + 2]) : "v"(gp_ + 2048));   \
  }

template <int F32>
__global__ __launch_bounds__(256, 1) void scan_kernel(
    const u16* __restrict__ gsum, const void* __restrict__ Whhv, const void* __restrict__ bhhv,
    u16* __restrict__ h0buf, u16* __restrict__ h1buf,
    void* __restrict__ outv, unsigned* __restrict__ bar, const unsigned* __restrict__ flag) {
  if ((*flag != 0u) != (F32 != 0)) return;   // uniform self-gate
  extern __shared__ u16 wlds[];  // 48*1024 bf16 = 96KB
  const int t = threadIdx.x, w = blockIdx.x;
  const int j0 = w * 16;
  // stage weights (once): row q = g*16+i  <- Whh[g*1024 + j0 + i][:], byte ^= (i<<4)
  for (int c = t; c < 48 * 128; c += 256) {
    int q = c >> 7, chunk = c & 127;
    int g = q >> 4, i = q & 15;
    short8 v;
    if (F32) {
      const float* wf = (const float*)Whhv + ((size_t)(g * 1024 + j0 + i)) * 1024 + chunk * 8;
      f32x4 a = *(const f32x4*)wf, b = *(const f32x4*)(wf + 4);
#pragma unroll
      for (int j = 0; j < 4; ++j) { v[j] = (short)f2bf(a[j]); v[4 + j] = (short)f2bf(b[j]); }
    } else {
      v = *(const short8*)((const u16*)Whhv + ((size_t)(g * 1024 + j0 + i)) * 1024 + chunk * 8);
    }
    *(short8*)((char*)wlds + q * 2048 + ((chunk * 16) ^ (i << 4))) = v;
  }
  const int lane = t & 63;
  const int bi = lane & 15;
  const int quad = lane >> 4;
  const int jl = j0 + bi;
  const int mb = (t >> 6) * 16;
  const float bhr = ldval<F32>(bhhv, (size_t)jl);
  const float bhi = ldval<F32>(bhhv, (size_t)(1024 + jl));
  const float bhn = ldval<F32>(bhhv, (size_t)(2048 + jl));
  __syncthreads();

  float hreg[4] = {0.f, 0.f, 0.f, 0.f};

  const int kb = quad * 16;                 // byte offset of lane's 16B k-chunk
  const int sw = bi << 4;                   // full-rank XOR swizzle
  const char* wbytes = (const char*)wlds;
  const char* s0 = wbytes + (size_t)(0 + bi) * 2048;
  const char* s1 = wbytes + (size_t)(16 + bi) * 2048;
  const char* s2 = wbytes + (size_t)(32 + bi) * 2048;

  unsigned pgu[12];
  // prologue: gsum for step 0, drained before loop
  ISSUE_GSUM(0);
  asm volatile("s_waitcnt vmcnt(0)" ::: "memory");
  SB0();

  short8 aA[8], aB[8], aC[8], aD[8];
  for (int s = 0; s < 256; ++s) {
    f32x4 ar = {0.f, 0.f, 0.f, 0.f};
    f32x4 ai = {0.f, 0.f, 0.f, 0.f};
    f32x4 an = {0.f, 0.f, 0.f, 0.f};
    if (s > 0) {
      // outstanding: 16 older (4 out + 12 gsum) + 32 h loads -> counted consume
      asm volatile("s_waitcnt vmcnt(24)" ::: "memory");
      SB0();
      CONSUME8(aA, 0);
      asm volatile("s_waitcnt vmcnt(16)" ::: "memory");
      SB0();
      CONSUME8(aB, 8);
      asm volatile("s_waitcnt vmcnt(8)" ::: "memory");
      SB0();
      CONSUME8(aC, 16);
      asm volatile("s_waitcnt vmcnt(0)" ::: "memory");
      SB0();
      CONSUME8(aD, 24);
      SB0();
    }
    u16* hw = (s & 1) ? h0buf : h1buf;
#pragma unroll
    for (int r = 0; r < 4; ++r) {
      int b = mb + quad * 4 + r;
      size_t m = (size_t)b * 256 + s;
      float rg = sigmoidf_(bf2f_u(pgu[r * 3 + 0]) + ar[r] + bhr);
      float ig = sigmoidf_(bf2f_u(pgu[r * 3 + 1]) + ai[r] + bhi);
      float ng = tanhf_(bf2f_u(pgu[r * 3 + 2]) + rg * (an[r] + bhn));
      float hy = ng + ig * (hreg[r] - ng);
      hreg[r] = hy;
      unsigned hv = (unsigned)f2bf(hy);
      if (s < 255) {  // h exchange: write-through to coherence point
        asm volatile("global_store_short %0, %1, off sc0 sc1"
                     :: "v"(hw + (size_t)b * 1024 + jl), "v"(hv) : "memory");
      }
      if (F32) {
        float hyv = hy;
        asm volatile("global_store_dword %0, %1, off nt"
                     :: "v"((float*)outv + m * 1024 + jl), "v"(hyv) : "memory");
      } else {
        asm volatile("global_store_short %0, %1, off nt"
                     :: "v"((u16*)outv + m * 1024 + jl), "v"(hv) : "memory");
      }
    }
    if (s < 255) {
      ISSUE_GSUM(s + 1);
      // wait ONLY the 4 h stores (oldest of [4 hst, 4 out, 12 gsum] = 20)
      asm volatile("s_waitcnt vmcnt(16)" ::: "memory");
      SB0();
      __builtin_amdgcn_s_barrier();          // raw: no compiler vmcnt(0) drain
      if (t == 0) {
        unsigned one = 1;
        asm volatile("global_atomic_add %0, %1, off" :: "v"(bar), "v"(one) : "memory");
        unsigned v;
        do {
          __builtin_amdgcn_s_sleep(1);
          asm volatile("global_load_dword %0, %1, off sc0 sc1\n\ts_waitcnt vmcnt(0)"
                       : "=v"(v) : "v"(bar) : "memory");
        } while (v < (unsigned)(64 * (s + 1)));
      }
      __builtin_amdgcn_s_barrier();
      // issue h loads for s+1 (consumed at top of next iter)
      const u16* hcur = (s & 1) ? h0buf : h1buf;   // buffer written this step
      const u16* ap = hcur + (size_t)(mb + bi) * 1024 + quad * 8;
      SB0();
      ISSUE8(aA, 0);
      ISSUE8(aB, 8);
      ISSUE8(aC, 16);
      ISSUE8(aD, 24);
      SB0();
    }
  }
#pragma unroll
  for (int r = 0; r < 4; ++r) {
    int b = mb + quad * 4 + r;
    if (F32) ((float*)outv)[NOUT + (size_t)b * 1024 + jl] = hreg[r];
    else     ((u16*)outv)[NOUT + (size_t)b * 1024 + jl] = f2bf(hreg[r]);
  }
}

extern "C" void kernel_launch(void* const* d_in, const int* in_sizes, int n_in,
                              void* d_out, int out_size, void* d_ws, size_t ws_size,
                              hipStream_t stream) {
  if (ws_size < WS_NEED) return;
  const void* x   = d_in[0];
  const void* f0  = d_in[1];
  const void* f1  = d_in[2];
  const void* wih = d_in[3];
  const void* whh = d_in[4];
  const void* wf0 = d_in[5];
  const void* wf1 = d_in[6];
  const void* bih = d_in[7];
  const void* bhh = d_in[8];
  const void* bf0 = d_in[9];
  const void* bf1 = d_in[10];

  char* ws = (char*)d_ws;
  u16* gsum = (u16*)(ws + OFF_GSUM);
  u16* hb0 = (u16*)(ws + OFF_HB0);
  u16* hb1 = (u16*)(ws + OFF_HB1);
  unsigned* bar = (unsigned*)(ws + OFF_BAR);
  unsigned* flag = (unsigned*)(ws + OFF_FLAG);

  hipMemsetAsync(bar, 0, 128, stream);      // bar + flag region
  hipMemsetAsync(hb0, 0, 131072, stream);   // deterministic h buffers each launch
  hipMemsetAsync(hb1, 0, 131072, stream);

  detect_kernel<<<dim3(1), dim3(64), 0, stream>>>((const u16*)wih, flag);

  gemm_fused<0><<<dim3(3072), dim3(256), 0, stream>>>(x, f0, f1, wih, wf0, wf1, bih, bf0, bf1, gsum, flag);
  gemm_fused<1><<<dim3(3072), dim3(256), 0, stream>>>(x, f0, f1, wih, wf0, wf1, bih, bf0, bf1, gsum, flag);

  hipFuncSetAttribute(reinterpret_cast<const void*>(&scan_kernel<0>),
                      hipFuncAttributeMaxDynamicSharedMemorySize, 98304);
  hipFuncSetAttribute(reinterpret_cast<const void*>(&scan_kernel<1>),
                      hipFuncAttributeMaxDynamicSharedMemorySize, 98304);
  scan_kernel<0><<<dim3(64), dim3(256), 98304, stream>>>(gsum, whh, bhh, hb0, hb1, d_out, bar, flag);
  scan_kernel<1><<<dim3(64), dim3(256), 98304, stream>>>(gsum, whh, bhh, hb0, hb1, d_out, bar, flag);
}